// Round 8
// baseline (280.999 us; speedup 1.0000x reference)
//
#include <hip/hip_runtime.h>
#include <hip/hip_bf16.h>
#include <math.h>

// Problem constants
#define N_  2
#define H_  8
#define G_  16      // N_*H_
#define L_  1024
#define S_  1024
#define E_  64
#define NC_ 6

typedef __attribute__((ext_vector_type(4))) float floatx4;
typedef __attribute__((ext_vector_type(8))) short short8;

#define MFMA16 __builtin_amdgcn_mfma_f32_16x16x32_bf16

// ---------------- workspace layout (bytes) ----------------
#define AHAT_OFF   0
#define AHAT_BYTES (NC_*G_*L_*128*2)          // 25,165,824
#define KHAT_OFF   (AHAT_OFF + AHAT_BYTES)
#define KHAT_BYTES (G_*S_*128*2)              //  4,194,304
#define PI_OFF     (KHAT_OFF + KHAT_BYTES)    // pi_t: [c][g][l] f32
#define PI_BYTES   (NC_*G_*L_*4)
#define HSQ_OFF    (PI_OFF + PI_BYTES)        // hsq: [c][g][l] f32
#define HSQ_BYTES  (NC_*G_*L_*4)
#define KSQ_OFF    (HSQ_OFF + HSQ_BYTES)      // ksq: [g][s] f32
#define KSQ_BYTES  (G_*S_*4)

// ---------------------------------------------------------------------------
// K1: merged prep. Per block (512 total): (a) 32 key rows -> Khat hi/lo + ksq;
// (b) pi softmax, htilde=tanh(q@C), bf16 hi/lo split, |htilde|^2.
// ---------------------------------------------------------------------------
__global__ __launch_bounds__(256) void k_prep(
    const float* __restrict__ q, const float* __restrict__ key,
    const float* __restrict__ M, const float* __restrict__ C,
    __hip_bfloat16* __restrict__ Ahat, __hip_bfloat16* __restrict__ Khat,
    float* __restrict__ ksq, float* __restrict__ pi_t, float* __restrict__ hsq) {
  extern __shared__ char smraw[];
  float* qs    = (float*)smraw;          // [32][65]
  float* Cs    = qs + 32*65;             // [3][4104]
  float* hsq_s = Cs + 3*4104;            // [6][32]
  float* pm    = hsq_s + 6*32;           // [32][8]

  int b  = blockIdx.x;
  int n  = b >> 8; int h = (b >> 5) & 7; int lc = b & 31;
  int l0 = lc * 32; int g = n*8 + h;
  int t  = threadIdx.x;

  // ---- prep_k part: 32 key rows per block (registers only) ----
  {
    int wv = t >> 6; int lane = t & 63;
    #pragma unroll
    for (int j = 0; j < 8; j++) {
      int r = b*32 + wv*8 + j;
      int kg = r >> 10; int s = r & 1023; int kn = kg >> 3; int kh = kg & 7;
      float v = key[(((size_t)(kn*S_ + s))*H_ + kh)*E_ + lane];
      __hip_bfloat16 hi = __float2bfloat16(v);
      __hip_bfloat16 lo = __float2bfloat16(v - __bfloat162float(hi));
      size_t base = ((size_t)kg*S_ + s)*128;
      Khat[base + lane]      = hi;
      Khat[base + 64 + lane] = lo;
      float sq = v*v;
      #pragma unroll
      for (int off = 32; off; off >>= 1) sq += __shfl_xor(sq, off);
      if (lane == 0) ksq[(size_t)kg*S_ + s] = sq;
    }
  }

  if (t < 192) hsq_s[t] = 0.0f;
  {
    int u = t;
    #pragma unroll
    for (int rep = 0; rep < 2; rep++, u += 256) {
      int row = u >> 4, seg = u & 15;
      float4 v = *(const float4*)(q + (((size_t)(n*L_ + l0 + row))*H_ + h)*E_ + seg*4);
      float* dst = qs + row*65 + seg*4;
      dst[0]=v.x; dst[1]=v.y; dst[2]=v.z; dst[3]=v.w;
    }
  }
  for (int gc = 0; gc < 2; gc++) {
    __syncthreads();
    for (int u = t; u < 3072; u += 256) {
      int cc = u >> 10; int rem = u & 1023; int e = rem >> 4; int seg = rem & 15;
      float4 v = *(const float4*)(C + (((size_t)((gc*3+cc)*8 + h))*64 + e)*64 + seg*4);
      float* dst = Cs + cc*4104 + e*64 + seg*4;
      dst[0]=v.x; dst[1]=v.y; dst[2]=v.z; dst[3]=v.w;
    }
    __syncthreads();
    if (t < 192) {
      int cc = t >> 6; int tt = t & 63; int lg = tt >> 3; int fg = tt & 7;
      int c = gc*3 + cc;
      float acc[4][8];
      #pragma unroll
      for (int i = 0; i < 4; i++)
        #pragma unroll
        for (int j = 0; j < 8; j++) acc[i][j] = 0.0f;
      for (int e = 0; e < 64; e++) {
        float c8[8];
        #pragma unroll
        for (int j = 0; j < 8; j++) c8[j] = Cs[cc*4104 + e*64 + fg*8 + j];
        #pragma unroll
        for (int i = 0; i < 4; i++) {
          float qv = qs[(lg*4+i)*65 + e];
          #pragma unroll
          for (int j = 0; j < 8; j++) acc[i][j] = fmaf(qv, c8[j], acc[i][j]);
        }
      }
      #pragma unroll
      for (int i = 0; i < 4; i++) {
        int l = l0 + lg*4 + i;
        size_t rowb = (((size_t)(c*G_ + g))*L_ + l) * 128;
        float ss = 0.0f;
        short8 hi8, lo8;
        #pragma unroll
        for (int j = 0; j < 8; j++) {
          float hv = tanhf(acc[i][j]);
          ss += hv*hv;
          __hip_bfloat16 hi = __float2bfloat16(hv);
          __hip_bfloat16 lo = __float2bfloat16(hv - __bfloat162float(hi));
          short hs, ls;
          __builtin_memcpy(&hs, &hi, 2);
          __builtin_memcpy(&ls, &lo, 2);
          hi8[j] = hs; lo8[j] = ls;
        }
        *(short8*)((char*)Ahat + (rowb + fg*8)*2)      = hi8;
        *(short8*)((char*)Ahat + (rowb + 64 + fg*8)*2) = lo8;
        atomicAdd(&hsq_s[c*32 + lg*4 + i], ss);
      }
    }
  }
  if (t < 192) {
    int k = t >> 5; int l = t & 31;
    float p = 0.0f;
    for (int e = 0; e < 64; e++) p += qs[l*65 + e] * M[(h*64 + e)*6 + k];
    pm[l*8 + k] = p;
  }
  __syncthreads();
  if (t < 192) {
    int k = t >> 5; int l = t & 31;
    float mx = pm[l*8+0];
    #pragma unroll
    for (int kk = 1; kk < 6; kk++) mx = fmaxf(mx, pm[l*8+kk]);
    float den = 0.0f;
    #pragma unroll
    for (int kk = 0; kk < 6; kk++) den += __expf(pm[l*8+kk] - mx);
    float pv = __expf(pm[l*8+k] - mx) / den;
    size_t idx = ((size_t)(k*G_ + g))*L_ + l0 + l;
    pi_t[idx] = pv;
    hsq[idx]  = hsq_s[k*32 + l];
  }
}

// ---------------------------------------------------------------------------
// K2: fused stats+emit, 2 sweeps, DOUBLE-BUFFERED K staging (1 barrier/iter,
// prefetch tile st+1 into VGPRs while computing st — hides global latency
// that R7's load->vmcnt0->dswrite->barrier chain exposed, ~28% idle issue).
// ksq/klen/mask are direct per-lane global loads, prefetched 1 tile ahead.
// launch_bounds(256,2): (256,3) capped VGPR at 84 and spilled (R3-R5: FETCH
// 66->544 MB, 2.6x time). Vector staging, NOT global_load_lds (R4: DMA killed
// Khat L2 reuse).
// Math: flat Z for L,O,R,W (bounded numerators; O via rcp); P flat with +64
// shift (Z_P = sum e^{-ns+mv+64}: 1024*e^64=6e30 no overflow; flushed terms
// < e^{ns_min-151} relative — R3's failure was the UNSHIFTED sum); online
// (m,z) for Y only ((d+1)^2 unbounded above).
// ---------------------------------------------------------------------------
#define LDS_BUF0  0                      // 64*272 = 17408
#define LDS_BUF1  17408                  // 64*272 = 17408  (A6 24576 overlays both)
#define LDS_ZRED  34816                  // 4*96 f = 1536
#define LDS_MRED  36352                  // 4*96 f = 1536
#define LDS_CST   37888                  // 96 float2 = 768
#define LDS_HSQ   38656                  // 96 f = 384
#define LDS_PI    39040                  // 96 f = 384
#define LDS_TOTAL 39424                  // 4 blocks/CU by LDS

__global__ __launch_bounds__(256, 2) void k_main(
    const __hip_bfloat16* __restrict__ Ahat, const __hip_bfloat16* __restrict__ Khat,
    const float* __restrict__ hsq, const float* __restrict__ ksq,
    const float* __restrict__ mask, const float* __restrict__ klen,
    const float* __restrict__ pi_t, float* __restrict__ out) {
  extern __shared__ char smraw[];
  char*   A6     = smraw;                          // staging overlay on BUF0/1
  float*  zred   = (float*)(smraw + LDS_ZRED);
  float*  mred   = (float*)(smraw + LDS_MRED);
  float2* cst    = (float2*)(smraw + LDS_CST);
  float*  hsq_s  = (float*)(smraw + LDS_HSQ);
  float*  pi_s   = (float*)(smraw + LDS_PI);

  const int l0 = blockIdx.x * 16; const int g = blockIdx.y; const int n = g >> 3;
  const int t = threadIdx.x; const int w = t >> 6; const int lane = t & 63;
  const int quad = lane >> 4; const int lc = lane & 15;
  const char* Kg = (const char*)Khat + ((size_t)g)*S_*256;

  // ---- stage A6 (6 codes x 16 rows x 256B) via vector loads ----
  #pragma unroll
  for (int rep = 0; rep < 6; rep++) {
    int u = t + rep*256; int cc = u >> 8; int rem = u & 255;
    int row = rem >> 4; int seg = rem & 15;
    *(int4*)(A6 + cc*4096 + row*256 + seg*16) =
      *(const int4*)((const char*)Ahat + (((size_t)(cc*G_+g))*L_ + l0 + row)*256 + seg*16);
  }
  if (t < 96) {
    size_t idx = ((size_t)((t >> 4)*G_ + g))*L_ + l0 + (t & 15);
    hsq_s[t] = hsq[idx];
    pi_s[t]  = pi_t[idx];
  }
  __syncthreads();

  short8 a6f[6][4];
  #pragma unroll
  for (int cc = 0; cc < 6; cc++)
    #pragma unroll
    for (int kt = 0; kt < 4; kt++)
      a6f[cc][kt] = *(const short8*)(A6 + cc*4096 + lc*256 + kt*64 + quad*16);

  // per-(c,i) constants
  float h1p[4], nh2[4], h4h[4], nh5[4];
  #pragma unroll
  for (int i = 0; i < 4; i++) {
    int r = quad*4 + i;
    h1p[i] = 1.0f + hsq_s[1*16 + r];
    nh2[i] = 64.0f - hsq_s[2*16 + r];    // +64 shift folded into P's constant
    h4h[i] = -0.5f * hsq_s[4*16 + r];
    nh5[i] = -hsq_s[5*16 + r];
  }
  __syncthreads();   // a6f/consts read done before buf0 write overlays A6

  // Flat Z: Zc[0..3]={L,O,R,W}, zp=P(shifted). Online: (m3,z3)=Y.
  float Zc[4][4], zp[4];
  float m3[4], z3[4];
  #pragma unroll
  for (int i = 0; i < 4; i++) {
    #pragma unroll
    for (int c = 0; c < 4; c++) Zc[c][i] = 0.0f;
    zp[i] = 0.0f; m3[i] = -INFINITY; z3[i] = 0.0f;
  }

  const int scol_base = w*16 + lc;
  int4 kreg[4];
  float mkN[4], kqN, klvN;

  // ---- prime tile 0 ----
  #pragma unroll
  for (int rep = 0; rep < 4; rep++) {
    int u = t + rep*256; int row = u >> 4, seg = u & 15;
    kreg[rep] = *(const int4*)(Kg + (size_t)row*256 + seg*16);
  }
  kqN  = ksq[(size_t)g*S_ + scol_base];
  klvN = klen[(size_t)n*S_ + scol_base];
  #pragma unroll
  for (int i = 0; i < 4; i++)
    mkN[i] = mask[((size_t)(n*L_ + l0 + quad*4 + i))*S_ + scol_base];

  // ================= sweep 1: Z =================
  #pragma unroll 1
  for (int st = 0; st < 16; st++) {
    char* buf = smraw + ((st & 1) ? LDS_BUF1 : LDS_BUF0);
    #pragma unroll
    for (int rep = 0; rep < 4; rep++) {
      int u = t + rep*256; int row = u >> 4, seg = u & 15;
      *(int4*)(buf + row*272 + seg*16) = kreg[rep];
    }
    float kq = kqN, klv = klvN;
    float mv[4];
    #pragma unroll
    for (int i = 0; i < 4; i++) mv[i] = mkN[i] + klv;
    __syncthreads();
    if (st < 15) {   // prefetch tile st+1 (full body to land)
      int s1 = (st+1)*64;
      #pragma unroll
      for (int rep = 0; rep < 4; rep++) {
        int u = t + rep*256; int row = u >> 4, seg = u & 15;
        kreg[rep] = *(const int4*)(Kg + (size_t)(s1 + row)*256 + seg*16);
      }
      int sc1 = s1 + scol_base;
      kqN  = ksq[(size_t)g*S_ + sc1];
      klvN = klen[(size_t)n*S_ + sc1];
      #pragma unroll
      for (int i = 0; i < 4; i++)
        mkN[i] = mask[((size_t)(n*L_ + l0 + quad*4 + i))*S_ + sc1];
    }
    short8 bfr[4];
    #pragma unroll
    for (int kt = 0; kt < 4; kt++)
      bfr[kt] = *(const short8*)(buf + (w*16 + lc)*272 + kt*64 + quad*16);
    float Ev[4], oc[4], pc[4], rc[4], wc[4];
    #pragma unroll
    for (int i = 0; i < 4; i++) {
      Ev[i] = __expf(mv[i]);
      oc[i] = h1p[i] + kq;
      pc[i] = nh2[i] - kq + mv[i];
      rc[i] = fmaf(-0.5f, kq, h4h[i]);
      wc[i] = nh5[i] - kq;
    }
    #pragma unroll
    for (int c = 0; c < 6; c++) {
      floatx4 a = {0.f, 0.f, 0.f, 0.f};
      a = MFMA16(a6f[c][0], bfr[0], a, 0,0,0);
      a = MFMA16(a6f[c][1], bfr[1], a, 0,0,0);
      a = MFMA16(a6f[c][0], bfr[2], a, 0,0,0);
      a = MFMA16(a6f[c][1], bfr[3], a, 0,0,0);
      a = MFMA16(a6f[c][2], bfr[0], a, 0,0,0);
      a = MFMA16(a6f[c][3], bfr[1], a, 0,0,0);
      #pragma unroll
      for (int i = 0; i < 4; i++) {
        float d = a[i];
        if (c == 0) {
          Zc[0][i] = fmaf(Ev[i], __expf(d), Zc[0][i]);
        } else if (c == 1) {
          Zc[1][i] = fmaf(Ev[i], __builtin_amdgcn_rcpf(fmaf(-2.f, d, oc[i])), Zc[1][i]);
        } else if (c == 2) {                              // P flat, shifted
          zp[i] += __expf(fmaf(2.f, d, pc[i]));
        } else if (c == 3) {                              // Y online
          float tt = d + 1.f;
          float x  = fmaf(tt, tt, mv[i]);
          float mn = fmaxf(m3[i], x);
          float e  = __expf(fminf(m3[i], x) - mn);
          z3[i] = (x > m3[i]) ? fmaf(z3[i], e, 1.0f) : (z3[i] + e);
          m3[i] = mn;
        } else if (c == 4) {
          Zc[2][i] = fmaf(Ev[i], __expf(__expf(d + rc[i])), Zc[2][i]);
        } else {
          float a5 = fmaf(2.f, d, wc[i]);
          Zc[3][i] = fmaf(Ev[i], __expf(__cosf(a5) * __expf(a5)), Zc[3][i]);
        }
      }
    }
  }

  // ---- reduce across 16 lanes (butterfly) ----
  #pragma unroll
  for (int off = 1; off < 16; off <<= 1) {
    #pragma unroll
    for (int c = 0; c < 4; c++)
      #pragma unroll
      for (int i = 0; i < 4; i++) Zc[c][i] += __shfl_xor(Zc[c][i], off);
    #pragma unroll
    for (int i = 0; i < 4; i++) {
      zp[i] += __shfl_xor(zp[i], off);
      float mo = __shfl_xor(m3[i], off);
      float zo = __shfl_xor(z3[i], off);
      float mn = fmaxf(m3[i], mo);
      float e  = __expf(fminf(m3[i], mo) - mn);
      z3[i] = (mo > m3[i]) ? fmaf(z3[i], e, zo) : fmaf(zo, e, z3[i]);
      m3[i] = mn;
    }
  }
  if (lc == 0) {
    static const int cmap[4] = {0, 1, 4, 5};
    #pragma unroll
    for (int c = 0; c < 4; c++)
      #pragma unroll
      for (int i = 0; i < 4; i++) {
        zred[w*96 + cmap[c]*16 + quad*4 + i] = Zc[c][i];
        mred[w*96 + cmap[c]*16 + quad*4 + i] = 0.f;
      }
    #pragma unroll
    for (int i = 0; i < 4; i++) {
      zred[w*96 + 2*16 + quad*4 + i] = zp[i];
      mred[w*96 + 2*16 + quad*4 + i] = 0.f;
      zred[w*96 + 3*16 + quad*4 + i] = z3[i];
      mred[w*96 + 3*16 + quad*4 + i] = m3[i];
    }
  }
  // ---- re-prime tile 0 for sweep 2 (latency hidden under reduction) ----
  #pragma unroll
  for (int rep = 0; rep < 4; rep++) {
    int u = t + rep*256; int row = u >> 4, seg = u & 15;
    kreg[rep] = *(const int4*)(Kg + (size_t)row*256 + seg*16);
  }
  kqN  = ksq[(size_t)g*S_ + scol_base];
  klvN = klen[(size_t)n*S_ + scol_base];
  #pragma unroll
  for (int i = 0; i < 4; i++)
    mkN[i] = mask[((size_t)(n*L_ + l0 + quad*4 + i))*S_ + scol_base];
  __syncthreads();
  if (t < 96) {
    int c = t >> 4;
    float z = zred[t], m = mred[t];
    if (c == 3) {
      #pragma unroll
      for (int w2 = 1; w2 < 4; w2++) {
        float mo = mred[w2*96 + t], zo = zred[w2*96 + t];
        float mn = fmaxf(m, mo);
        float e  = __expf(fminf(m, mo) - mn);
        z = (mo > m) ? fmaf(z, e, zo) : fmaf(zo, e, z);
        m = mn;
      }
    } else {
      #pragma unroll
      for (int w2 = 1; w2 < 4; w2++) z += zred[w2*96 + t];
    }
    cst[t] = make_float2(pi_s[t] / z, m);
  }
  __syncthreads();

  float ac[6][4], m3f[4];
  #pragma unroll
  for (int c = 0; c < 6; c++)
    #pragma unroll
    for (int i = 0; i < 4; i++) {
      float2 v = cst[c*16 + quad*4 + i];
      ac[c][i] = v.x;
      if (c == 3) m3f[i] = v.y;
    }

  // ================= sweep 2: emit =================
  #pragma unroll 1
  for (int st = 0; st < 16; st++) {
    char* buf = smraw + ((st & 1) ? LDS_BUF1 : LDS_BUF0);
    #pragma unroll
    for (int rep = 0; rep < 4; rep++) {
      int u = t + rep*256; int row = u >> 4, seg = u & 15;
      *(int4*)(buf + row*272 + seg*16) = kreg[rep];
    }
    float kq = kqN, klv = klvN;
    float mv[4];
    #pragma unroll
    for (int i = 0; i < 4; i++) mv[i] = mkN[i] + klv;
    int scol = st*64 + scol_base;
    __syncthreads();
    if (st < 15) {
      int s1 = (st+1)*64;
      #pragma unroll
      for (int rep = 0; rep < 4; rep++) {
        int u = t + rep*256; int row = u >> 4, seg = u & 15;
        kreg[rep] = *(const int4*)(Kg + (size_t)(s1 + row)*256 + seg*16);
      }
      int sc1 = s1 + scol_base;
      kqN  = ksq[(size_t)g*S_ + sc1];
      klvN = klen[(size_t)n*S_ + sc1];
      #pragma unroll
      for (int i = 0; i < 4; i++)
        mkN[i] = mask[((size_t)(n*L_ + l0 + quad*4 + i))*S_ + sc1];
    }
    short8 bfr[4];
    #pragma unroll
    for (int kt = 0; kt < 4; kt++)
      bfr[kt] = *(const short8*)(buf + (w*16 + lc)*272 + kt*64 + quad*16);
    float Ev[4], oc[4], pc[4], rc[4], wc[4];
    #pragma unroll
    for (int i = 0; i < 4; i++) {
      Ev[i] = __expf(mv[i]);
      oc[i] = h1p[i] + kq;
      pc[i] = nh2[i] - kq + mv[i];
      rc[i] = fmaf(-0.5f, kq, h4h[i]);
      wc[i] = nh5[i] - kq;
    }
    float Sacc[4] = {0.f, 0.f, 0.f, 0.f};   // Ev-scaled flat codes (L,O,R,W)
    float G[4]    = {0.f, 0.f, 0.f, 0.f};   // P (mv folded) + Y (online)
    #pragma unroll
    for (int c = 0; c < 6; c++) {
      floatx4 a = {0.f, 0.f, 0.f, 0.f};
      a = MFMA16(a6f[c][0], bfr[0], a, 0,0,0);
      a = MFMA16(a6f[c][1], bfr[1], a, 0,0,0);
      a = MFMA16(a6f[c][0], bfr[2], a, 0,0,0);
      a = MFMA16(a6f[c][1], bfr[3], a, 0,0,0);
      a = MFMA16(a6f[c][2], bfr[0], a, 0,0,0);
      a = MFMA16(a6f[c][3], bfr[1], a, 0,0,0);
      #pragma unroll
      for (int i = 0; i < 4; i++) {
        float d = a[i];
        if (c == 0) {
          Sacc[i] = fmaf(ac[0][i], __expf(d), Sacc[i]);
        } else if (c == 1) {
          Sacc[i] = fmaf(ac[1][i], __builtin_amdgcn_rcpf(fmaf(-2.f, d, oc[i])), Sacc[i]);
        } else if (c == 2) {
          G[i] = fmaf(ac[2][i], __expf(fmaf(2.f, d, pc[i])), G[i]);
        } else if (c == 3) {
          float tt = d + 1.f;
          float x  = fmaf(tt, tt, mv[i]);
          G[i] = fmaf(ac[3][i], __expf(x - m3f[i]), G[i]);
        } else if (c == 4) {
          Sacc[i] = fmaf(ac[4][i], __expf(__expf(d + rc[i])), Sacc[i]);
        } else {
          float a5 = fmaf(2.f, d, wc[i]);
          Sacc[i] = fmaf(ac[5][i], __expf(__cosf(a5) * __expf(a5)), Sacc[i]);
        }
      }
    }
    #pragma unroll
    for (int i = 0; i < 4; i++)
      out[(((size_t)g)*L_ + l0 + quad*4 + i)*S_ + scol] = fmaf(Ev[i], Sacc[i], G[i]);
  }
}

// ---------------------------------------------------------------------------
extern "C" void kernel_launch(void* const* d_in, const int* in_sizes, int n_in,
                              void* d_out, int out_size, void* d_ws, size_t ws_size,
                              hipStream_t stream) {
  (void)in_sizes; (void)n_in; (void)out_size; (void)ws_size;
  const float* q    = (const float*)d_in[0];
  const float* key  = (const float*)d_in[1];
  const float* mask = (const float*)d_in[2];
  const float* klen = (const float*)d_in[3];
  const float* M    = (const float*)d_in[4];
  const float* C    = (const float*)d_in[5];
  char* ws = (char*)d_ws;
  __hip_bfloat16* Ahat = (__hip_bfloat16*)(ws + AHAT_OFF);
  __hip_bfloat16* Khat = (__hip_bfloat16*)(ws + KHAT_OFF);
  float* pi_t    = (float*)(ws + PI_OFF);
  float* hsq     = (float*)(ws + HSQ_OFF);
  float* ksq     = (float*)(ws + KSQ_OFF);
  float* out = (float*)d_out;

  k_prep<<<512, 256, 59360, stream>>>(q, key, M, C, Ahat, Khat, ksq, pi_t, hsq);
  k_main<<<dim3(64, 16), 256, LDS_TOTAL, stream>>>(Ahat, Khat, hsq, ksq, mask, klen,
                                                   pi_t, out);
}

// Round 10
// 223.225 us; speedup vs baseline: 1.2588x; 1.2588x over previous
//
#include <hip/hip_runtime.h>
#include <hip/hip_bf16.h>
#include <math.h>

// Problem constants
#define N_  2
#define H_  8
#define G_  16      // N_*H_
#define L_  1024
#define S_  1024
#define E_  64
#define NC_ 6

typedef __attribute__((ext_vector_type(4))) float floatx4;
typedef __attribute__((ext_vector_type(8))) short short8;

#define MFMA16 __builtin_amdgcn_mfma_f32_16x16x32_bf16

// ---------------- workspace layout (bytes) ----------------
#define AHAT_OFF   0
#define AHAT_BYTES (NC_*G_*L_*128*2)          // 25,165,824
#define KHAT_OFF   (AHAT_OFF + AHAT_BYTES)
#define KHAT_BYTES (G_*S_*128*2)              //  4,194,304
#define PI_OFF     (KHAT_OFF + KHAT_BYTES)    // pi_t: [c][g][l] f32
#define PI_BYTES   (NC_*G_*L_*4)
#define HSQ_OFF    (PI_OFF + PI_BYTES)        // hsq: [c][g][l] f32
#define HSQ_BYTES  (NC_*G_*L_*4)
#define KSQ_OFF    (HSQ_OFF + HSQ_BYTES)      // ksq: [g][s] f32
#define KSQ_BYTES  (G_*S_*4)

// fast tanh: 1 - 2/(e^{2x}+1). Saturates correctly at +-inf; ~1e-7 rel err,
// far below the bf16 hi/lo split quantization downstream.
__device__ __forceinline__ float ftanh(float x) {
  return 1.0f - 2.0f * __builtin_amdgcn_rcpf(__expf(2.0f*x) + 1.0f);
}

// ---------------------------------------------------------------------------
// K1: htilde = tanh(q @ C[c,h]) -> bf16 hi/lo split + |htilde|^2.
// grid (8 l-chunks of 128, 6 codes, 16 g), 256 thr. One code per block:
// all 256 threads compute, reg-blocked 4 rows x 8 cols, vectorized LDS reads.
// LDS 52224 -> 3 blocks/CU (768 blocks = exactly resident).
// ---------------------------------------------------------------------------
__global__ __launch_bounds__(256) void k_htilde(
    const float* __restrict__ q, const float* __restrict__ C,
    __hip_bfloat16* __restrict__ Ahat, float* __restrict__ hsq) {
  extern __shared__ char smraw[];
  float* qs = (float*)smraw;             // [128][68]
  float* Cs = qs + 128*68;               // [64][68]

  const int lch = blockIdx.x, c = blockIdx.y, g = blockIdx.z;
  const int n = g >> 3, h = g & 7;
  const int l0 = lch * 128;
  const int t = threadIdx.x;

  for (int u = t; u < 2048; u += 256) {          // q: 128 rows x 16 segs
    int row = u >> 4, seg = u & 15;
    *(float4*)(qs + row*68 + seg*4) =
      *(const float4*)(q + (((size_t)(n*L_ + l0 + row))*H_ + h)*E_ + seg*4);
  }
  for (int u = t; u < 1024; u += 256) {          // C[c][h]: 64 rows x 16 segs
    int e = u >> 4, seg = u & 15;
    *(float4*)(Cs + e*68 + seg*4) =
      *(const float4*)(C + (((size_t)(c*8 + h))*64 + e)*64 + seg*4);
  }
  __syncthreads();

  const int rg = t >> 3, fg = t & 7;    // 32 row-groups x 4 rows; 8 col-octets
  float acc[4][8];
  #pragma unroll
  for (int i = 0; i < 4; i++)
    #pragma unroll
    for (int j = 0; j < 8; j++) acc[i][j] = 0.0f;

  #pragma unroll 4
  for (int e0 = 0; e0 < 64; e0 += 4) {
    float4 q4[4];
    #pragma unroll
    for (int i = 0; i < 4; i++)
      q4[i] = *(const float4*)(qs + (rg*4 + i)*68 + e0);
    #pragma unroll
    for (int ee = 0; ee < 4; ee++) {
      float4 ca = *(const float4*)(Cs + (e0+ee)*68 + fg*8);
      float4 cb = *(const float4*)(Cs + (e0+ee)*68 + fg*8 + 4);
      float c8[8] = {ca.x, ca.y, ca.z, ca.w, cb.x, cb.y, cb.z, cb.w};
      #pragma unroll
      for (int i = 0; i < 4; i++) {
        float qv = (ee == 0) ? q4[i].x : (ee == 1) ? q4[i].y
                 : (ee == 2) ? q4[i].z : q4[i].w;
        #pragma unroll
        for (int j = 0; j < 8; j++) acc[i][j] = fmaf(qv, c8[j], acc[i][j]);
      }
    }
  }

  #pragma unroll
  for (int i = 0; i < 4; i++) {
    int l = l0 + rg*4 + i;
    size_t rowb = (((size_t)(c*G_ + g))*L_ + l) * 128;
    float ss = 0.0f;
    short8 hi8, lo8;
    #pragma unroll
    for (int j = 0; j < 8; j++) {
      float hv = ftanh(acc[i][j]);
      ss += hv*hv;
      __hip_bfloat16 hi = __float2bfloat16(hv);
      __hip_bfloat16 lo = __float2bfloat16(hv - __bfloat162float(hi));
      short hs, ls;
      __builtin_memcpy(&hs, &hi, 2);
      __builtin_memcpy(&ls, &lo, 2);
      hi8[j] = hs; lo8[j] = ls;
    }
    *(short8*)((char*)Ahat + (rowb + fg*8)*2)      = hi8;
    *(short8*)((char*)Ahat + (rowb + 64 + fg*8)*2) = lo8;
    ss += __shfl_xor(ss, 1); ss += __shfl_xor(ss, 2); ss += __shfl_xor(ss, 4);
    if (fg == 0) hsq[((size_t)(c*G_ + g))*L_ + l] = ss;
  }
}

// ---------------------------------------------------------------------------
// K2: pi = softmax_k(q @ M[h]). grid 64 (16 g x 4 l-chunks of 256), 256 thr.
// R9 BUG FIXED: Ms has 384 entries but the block has 256 threads — the old
// `if (t < 384)` left Ms[256..383] uninitialized (absmax 1.0). Strided loop.
// ---------------------------------------------------------------------------
__global__ __launch_bounds__(256) void k_pi(
    const float* __restrict__ q, const float* __restrict__ M,
    float* __restrict__ pi_t) {
  __shared__ float Ms[384];
  const int g = blockIdx.x >> 2, lch = blockIdx.x & 3;
  const int n = g >> 3, h = g & 7;
  const int t = threadIdx.x;
  const int l = lch*256 + t;
  for (int u = t; u < 384; u += 256) Ms[u] = M[h*384 + u];  // M[h][e][k]
  __syncthreads();
  const float* qrow = q + (((size_t)(n*L_ + l))*H_ + h)*E_;
  float p[6] = {0.f, 0.f, 0.f, 0.f, 0.f, 0.f};
  #pragma unroll 8
  for (int e = 0; e < 64; e++) {
    float qv = qrow[e];
    #pragma unroll
    for (int k = 0; k < 6; k++) p[k] = fmaf(qv, Ms[e*6 + k], p[k]);
  }
  float mx = p[0];
  #pragma unroll
  for (int k = 1; k < 6; k++) mx = fmaxf(mx, p[k]);
  float den = 0.f;
  #pragma unroll
  for (int k = 0; k < 6; k++) den += __expf(p[k] - mx);
  float rden = __builtin_amdgcn_rcpf(den);
  #pragma unroll
  for (int k = 0; k < 6; k++)
    pi_t[((size_t)(k*G_ + g))*L_ + l] = __expf(p[k] - mx) * rden;
}

// ---------------------------------------------------------------------------
// K3: key split hi/lo + ksq. (R2-R7 proven)
// ---------------------------------------------------------------------------
__global__ __launch_bounds__(256) void k_key(
    const float* __restrict__ key, __hip_bfloat16* __restrict__ Khat,
    float* __restrict__ ksq) {
  int t = threadIdx.x; int wv = t >> 6; int lane = t & 63;
  int r = blockIdx.x*4 + wv;
  int g = r >> 10; int s = r & 1023; int n = g >> 3; int h = g & 7;
  float v = key[(((size_t)(n*S_ + s))*H_ + h)*E_ + lane];
  __hip_bfloat16 hi = __float2bfloat16(v);
  __hip_bfloat16 lo = __float2bfloat16(v - __bfloat162float(hi));
  size_t base = ((size_t)g*S_ + s)*128;
  Khat[base + lane]      = hi;
  Khat[base + 64 + lane] = lo;
  float sq = v*v;
  #pragma unroll
  for (int off = 32; off; off >>= 1) sq += __shfl_xor(sq, off);
  if (lane == 0) ksq[(size_t)g*S_ + s] = sq;
}

// ---------------------------------------------------------------------------
// K4: fused stats+emit, 2 sweeps — R7-EXACT loop structure (2 barriers/tile,
// single-buffer LDS staging; measured 134 µs). R8's VGPR-prefetch dbuf
// REGRESSED (184 µs: compiler defeats manual pipelining) — do not restructure.
// launch_bounds(256,2): (256,3) capped VGPR at 84 -> scratch spill disaster
// (R3-R5). Vector staging, NOT global_load_lds (R4: DMA killed L2 reuse).
// Math: flat Z for L,O,R,W (bounded numerators; O via rcp); P flat with +64
// shift (no overflow: 1024*e^64=6e30; R3's denormal-flush bug was the
// UNSHIFTED sum); online (m,z) for Y only.
// ---------------------------------------------------------------------------
#define LDS_K     0                      // 64*272 = 17408 (A6 24576 overlays)
#define LDS_KSQ   17408                  // 64 f
#define LDS_KLEN  17664                  // 64 f
#define LDS_ZRED  24576                  // 4*96 f = 1536
#define LDS_MRED  26112                  // 4*96 f = 1536
#define LDS_CST   27648                  // 96 float2 = 768
#define LDS_HSQ   28416                  // 96 f = 384
#define LDS_PI    28800                  // 96 f = 384
#define LDS_TOTAL 29184

__global__ __launch_bounds__(256, 2) void k_main(
    const __hip_bfloat16* __restrict__ Ahat, const __hip_bfloat16* __restrict__ Khat,
    const float* __restrict__ hsq, const float* __restrict__ ksq,
    const float* __restrict__ mask, const float* __restrict__ klen,
    const float* __restrict__ pi_t, float* __restrict__ out) {
  extern __shared__ char smraw[];
  char*   A6     = smraw;                          // staging overlay
  char*   K_lds  = smraw + LDS_K;
  float*  ksq_t  = (float*)(smraw + LDS_KSQ);
  float*  klen_t = (float*)(smraw + LDS_KLEN);
  float*  zred   = (float*)(smraw + LDS_ZRED);
  float*  mred   = (float*)(smraw + LDS_MRED);
  float2* cst    = (float2*)(smraw + LDS_CST);
  float*  hsq_s  = (float*)(smraw + LDS_HSQ);
  float*  pi_s   = (float*)(smraw + LDS_PI);

  const int l0 = blockIdx.x * 16; const int g = blockIdx.y; const int n = g >> 3;
  const int t = threadIdx.x; const int w = t >> 6; const int lane = t & 63;
  const int quad = lane >> 4; const int lc = lane & 15;

  // ---- stage A6 (6 codes x 16 rows x 256B) via vector loads ----
  #pragma unroll
  for (int rep = 0; rep < 6; rep++) {
    int u = t + rep*256; int cc = u >> 8; int rem = u & 255;
    int row = rem >> 4; int seg = rem & 15;
    *(int4*)(A6 + cc*4096 + row*256 + seg*16) =
      *(const int4*)((const char*)Ahat + (((size_t)(cc*G_+g))*L_ + l0 + row)*256 + seg*16);
  }
  if (t < 96) {
    size_t idx = ((size_t)((t >> 4)*G_ + g))*L_ + l0 + (t & 15);
    hsq_s[t] = hsq[idx];
    pi_s[t]  = pi_t[idx];
  }
  __syncthreads();

  short8 a6f[6][4];
  #pragma unroll
  for (int cc = 0; cc < 6; cc++)
    #pragma unroll
    for (int kt = 0; kt < 4; kt++)
      a6f[cc][kt] = *(const short8*)(A6 + cc*4096 + lc*256 + kt*64 + quad*16);

  // per-(c,i) constants
  float h1p[4], nh2[4], h4h[4], nh5[4];
  #pragma unroll
  for (int i = 0; i < 4; i++) {
    int r = quad*4 + i;
    h1p[i] = 1.0f + hsq_s[1*16 + r];
    nh2[i] = 64.0f - hsq_s[2*16 + r];    // P: +64 shift folded in
    h4h[i] = -0.5f * hsq_s[4*16 + r];
    nh5[i] = -hsq_s[5*16 + r];
  }

  // Flat Z: Zc[0..3]={L,O,R,W}, zp=P(shifted). Online: (m3,z3)=Y.
  float Zc[4][4], zp[4], m3[4], z3[4];
  #pragma unroll
  for (int i = 0; i < 4; i++) {
    #pragma unroll
    for (int c = 0; c < 4; c++) Zc[c][i] = 0.0f;
    zp[i] = 0.0f; m3[i] = -INFINITY; z3[i] = 0.0f;
  }

  // ================= sweep 1: Z =================
  #pragma unroll 1
  for (int st = 0; st < 16; st++) {
    int s0 = st*64;
    __syncthreads();                          // K_lds free (st=0: a6f reads done)
    #pragma unroll
    for (int rep = 0; rep < 4; rep++) {
      int u = t + rep*256; int row = u >> 4, seg = u & 15;
      *(int4*)(K_lds + row*272 + seg*16) =
        *(const int4*)((const char*)Khat + (((size_t)g)*S_ + s0 + row)*256 + seg*16);
    }
    if (t < 64) { ksq_t[t] = ksq[(size_t)g*S_ + s0 + t]; klen_t[t] = klen[(size_t)n*S_ + s0 + t]; }
    int scol = s0 + w*16 + lc;
    float mk[4];
    #pragma unroll
    for (int i = 0; i < 4; i++)    // issue before barrier: latency overlaps it
      mk[i] = mask[((size_t)(n*L_ + l0 + quad*4 + i))*S_ + scol];
    __syncthreads();
    short8 bfr[4];
    #pragma unroll
    for (int kt = 0; kt < 4; kt++)
      bfr[kt] = *(const short8*)(K_lds + (w*16 + lc)*272 + kt*64 + quad*16);
    float kq  = ksq_t[w*16 + lc];
    float klv = klen_t[w*16 + lc];
    float mv[4], Ev[4], oc[4], pc[4], rc[4], wc[4];
    #pragma unroll
    for (int i = 0; i < 4; i++) {
      mv[i] = mk[i] + klv;
      Ev[i] = __expf(mv[i]);
      oc[i] = h1p[i] + kq;
      pc[i] = nh2[i] - kq + mv[i];
      rc[i] = fmaf(-0.5f, kq, h4h[i]);
      wc[i] = nh5[i] - kq;
    }
    #pragma unroll
    for (int c = 0; c < 6; c++) {
      floatx4 a = {0.f, 0.f, 0.f, 0.f};
      a = MFMA16(a6f[c][0], bfr[0], a, 0,0,0);
      a = MFMA16(a6f[c][1], bfr[1], a, 0,0,0);
      a = MFMA16(a6f[c][0], bfr[2], a, 0,0,0);
      a = MFMA16(a6f[c][1], bfr[3], a, 0,0,0);
      a = MFMA16(a6f[c][2], bfr[0], a, 0,0,0);
      a = MFMA16(a6f[c][3], bfr[1], a, 0,0,0);
      #pragma unroll
      for (int i = 0; i < 4; i++) {
        float d = a[i];
        if (c == 0) {
          Zc[0][i] = fmaf(Ev[i], __expf(d), Zc[0][i]);
        } else if (c == 1) {
          Zc[1][i] = fmaf(Ev[i], __builtin_amdgcn_rcpf(fmaf(-2.f, d, oc[i])), Zc[1][i]);
        } else if (c == 2) {                              // P flat, shifted
          zp[i] += __expf(fmaf(2.f, d, pc[i]));
        } else if (c == 3) {                              // Y online
          float tt = d + 1.f;
          float x  = fmaf(tt, tt, mv[i]);
          float mn = fmaxf(m3[i], x);
          float e  = __expf(fminf(m3[i], x) - mn);
          z3[i] = (x > m3[i]) ? fmaf(z3[i], e, 1.0f) : (z3[i] + e);
          m3[i] = mn;
        } else if (c == 4) {
          Zc[2][i] = fmaf(Ev[i], __expf(__expf(d + rc[i])), Zc[2][i]);
        } else {
          float a5 = fmaf(2.f, d, wc[i]);
          Zc[3][i] = fmaf(Ev[i], __expf(__cosf(a5) * __expf(a5)), Zc[3][i]);
        }
      }
    }
  }

  // ---- reduce across 16 lanes (butterfly) ----
  #pragma unroll
  for (int off = 1; off < 16; off <<= 1) {
    #pragma unroll
    for (int c = 0; c < 4; c++)
      #pragma unroll
      for (int i = 0; i < 4; i++) Zc[c][i] += __shfl_xor(Zc[c][i], off);
    #pragma unroll
    for (int i = 0; i < 4; i++) {
      zp[i] += __shfl_xor(zp[i], off);
      float mo = __shfl_xor(m3[i], off);
      float zo = __shfl_xor(z3[i], off);
      float mn = fmaxf(m3[i], mo);
      float e  = __expf(fminf(m3[i], mo) - mn);
      z3[i] = (mo > m3[i]) ? fmaf(z3[i], e, zo) : fmaf(zo, e, z3[i]);
      m3[i] = mn;
    }
  }
  if (lc == 0) {
    static const int cmap[4] = {0, 1, 4, 5};
    #pragma unroll
    for (int c = 0; c < 4; c++)
      #pragma unroll
      for (int i = 0; i < 4; i++) {
        zred[w*96 + cmap[c]*16 + quad*4 + i] = Zc[c][i];
        mred[w*96 + cmap[c]*16 + quad*4 + i] = 0.f;
      }
    #pragma unroll
    for (int i = 0; i < 4; i++) {
      zred[w*96 + 2*16 + quad*4 + i] = zp[i];
      mred[w*96 + 2*16 + quad*4 + i] = 0.f;
      zred[w*96 + 3*16 + quad*4 + i] = z3[i];
      mred[w*96 + 3*16 + quad*4 + i] = m3[i];
    }
  }
  __syncthreads();
  if (t < 96) {
    int c = t >> 4;
    float z = zred[t], m = mred[t];
    if (c == 3) {
      #pragma unroll
      for (int w2 = 1; w2 < 4; w2++) {
        float mo = mred[w2*96 + t], zo = zred[w2*96 + t];
        float mn = fmaxf(m, mo);
        float e  = __expf(fminf(m, mo) - mn);
        z = (mo > m) ? fmaf(z, e, zo) : fmaf(zo, e, z);
        m = mn;
      }
    } else {
      #pragma unroll
      for (int w2 = 1; w2 < 4; w2++) z += zred[w2*96 + t];
    }
    cst[t] = make_float2(pi_s[t] / z, m);
  }
  __syncthreads();

  float ac[6][4], m3f[4];
  #pragma unroll
  for (int c = 0; c < 6; c++)
    #pragma unroll
    for (int i = 0; i < 4; i++) {
      float2 v = cst[c*16 + quad*4 + i];
      ac[c][i] = v.x;
      if (c == 3) m3f[i] = v.y;
    }

  // ================= sweep 2: emit =================
  #pragma unroll 1
  for (int st = 0; st < 16; st++) {
    int s0 = st*64;
    __syncthreads();
    #pragma unroll
    for (int rep = 0; rep < 4; rep++) {
      int u = t + rep*256; int row = u >> 4, seg = u & 15;
      *(int4*)(K_lds + row*272 + seg*16) =
        *(const int4*)((const char*)Khat + (((size_t)g)*S_ + s0 + row)*256 + seg*16);
    }
    if (t < 64) { ksq_t[t] = ksq[(size_t)g*S_ + s0 + t]; klen_t[t] = klen[(size_t)n*S_ + s0 + t]; }
    int scol = s0 + w*16 + lc;
    float mk[4];
    #pragma unroll
    for (int i = 0; i < 4; i++)
      mk[i] = mask[((size_t)(n*L_ + l0 + quad*4 + i))*S_ + scol];
    __syncthreads();
    short8 bfr[4];
    #pragma unroll
    for (int kt = 0; kt < 4; kt++)
      bfr[kt] = *(const short8*)(K_lds + (w*16 + lc)*272 + kt*64 + quad*16);
    float kq  = ksq_t[w*16 + lc];
    float klv = klen_t[w*16 + lc];
    float mv[4], Ev[4], oc[4], pc[4], rc[4], wc[4];
    #pragma unroll
    for (int i = 0; i < 4; i++) {
      mv[i] = mk[i] + klv;
      Ev[i] = __expf(mv[i]);
      oc[i] = h1p[i] + kq;
      pc[i] = nh2[i] - kq + mv[i];
      rc[i] = fmaf(-0.5f, kq, h4h[i]);
      wc[i] = nh5[i] - kq;
    }
    float Sacc[4] = {0.f, 0.f, 0.f, 0.f};   // Ev-scaled flat codes (L,O,R,W)
    float G[4]    = {0.f, 0.f, 0.f, 0.f};   // P (mv folded) + Y
    #pragma unroll
    for (int c = 0; c < 6; c++) {
      floatx4 a = {0.f, 0.f, 0.f, 0.f};
      a = MFMA16(a6f[c][0], bfr[0], a, 0,0,0);
      a = MFMA16(a6f[c][1], bfr[1], a, 0,0,0);
      a = MFMA16(a6f[c][0], bfr[2], a, 0,0,0);
      a = MFMA16(a6f[c][1], bfr[3], a, 0,0,0);
      a = MFMA16(a6f[c][2], bfr[0], a, 0,0,0);
      a = MFMA16(a6f[c][3], bfr[1], a, 0,0,0);
      #pragma unroll
      for (int i = 0; i < 4; i++) {
        float d = a[i];
        if (c == 0) {
          Sacc[i] = fmaf(ac[0][i], __expf(d), Sacc[i]);
        } else if (c == 1) {
          Sacc[i] = fmaf(ac[1][i], __builtin_amdgcn_rcpf(fmaf(-2.f, d, oc[i])), Sacc[i]);
        } else if (c == 2) {
          G[i] = fmaf(ac[2][i], __expf(fmaf(2.f, d, pc[i])), G[i]);
        } else if (c == 3) {
          float tt = d + 1.f;
          float x  = fmaf(tt, tt, mv[i]);
          G[i] = fmaf(ac[3][i], __expf(x - m3f[i]), G[i]);
        } else if (c == 4) {
          Sacc[i] = fmaf(ac[4][i], __expf(__expf(d + rc[i])), Sacc[i]);
        } else {
          float a5 = fmaf(2.f, d, wc[i]);
          Sacc[i] = fmaf(ac[5][i], __expf(__cosf(a5) * __expf(a5)), Sacc[i]);
        }
      }
    }
    #pragma unroll
    for (int i = 0; i < 4; i++)
      out[(((size_t)g)*L_ + l0 + quad*4 + i)*S_ + scol] = fmaf(Ev[i], Sacc[i], G[i]);
  }
}

// ---------------------------------------------------------------------------
extern "C" void kernel_launch(void* const* d_in, const int* in_sizes, int n_in,
                              void* d_out, int out_size, void* d_ws, size_t ws_size,
                              hipStream_t stream) {
  (void)in_sizes; (void)n_in; (void)out_size; (void)ws_size;
  const float* q    = (const float*)d_in[0];
  const float* key  = (const float*)d_in[1];
  const float* mask = (const float*)d_in[2];
  const float* klen = (const float*)d_in[3];
  const float* M    = (const float*)d_in[4];
  const float* C    = (const float*)d_in[5];
  char* ws = (char*)d_ws;
  __hip_bfloat16* Ahat = (__hip_bfloat16*)(ws + AHAT_OFF);
  __hip_bfloat16* Khat = (__hip_bfloat16*)(ws + KHAT_OFF);
  float* pi_t    = (float*)(ws + PI_OFF);
  float* hsq     = (float*)(ws + HSQ_OFF);
  float* ksq     = (float*)(ws + KSQ_OFF);
  float* out = (float*)d_out;

  k_htilde<<<dim3(8, 6, 16), 256, 52224, stream>>>(q, C, Ahat, hsq);
  k_key<<<4096, 256, 0, stream>>>(key, Khat, ksq);
  k_pi<<<64, 256, 0, stream>>>(q, M, pi_t);
  k_main<<<dim3(64, 16), 256, LDS_TOTAL, stream>>>(Ahat, Khat, hsq, ksq, mask, klen,
                                                   pi_t, out);
}